// Round 16
// baseline (128.889 us; speedup 1.0000x reference)
//
#include <hip/hip_runtime.h>

// WaveNet gated residual block, MI355X bf16-MFMA implementation (v16).
// v16 = v11 schedule (the verified best: k12 117us) with an LDS/occupancy
// restructure -- the one untested lever (all pipes <=26%, occupancy 38%,
// 2 blocks/CU LDS-capped):
//  1) granule-major LDS [granule][row][16B]: conflict-free on write AND read
//     for X, cond, z (contiguous 256B per 16-lane group; row stride shifts no
//     banks) -> all XOR swizzles + their VALU math deleted.
//  2) z tile overwrites the X region (X dead after k1; barrier C protects).
//  3) cond tile = 10 real granules; kc=2 pad fragments zero-predicated
//     (g>=2 lanes supply zero instead of reading a pad granule).
//  TT=112 (nf=7): LDS = 16*120*16 + 10*112*16 = 48,640B -> 3 blocks/CU.
//  Grid 143, last tile bounds-guarded. k1/k2 schedule identical to v11
//  (sched_barrier pins = load-batching regulators; v13/v14/v15 lesson:
//  any added register liveness at (512,4) spills).

#define NB 8
#define NT 16000
#define CIN 128
#define CCOND 80
#define TT 112
#define XR 120          // TT + 8 halo rows
#define XSTRIDE 1920    // XR*16 bytes per granule
#define CSTRIDE 1792    // 112*16 bytes per granule
#define NBLK 143        // ceil(NT/TT)

typedef __attribute__((ext_vector_type(8))) __bf16 bf16x8;
typedef __attribute__((ext_vector_type(4))) float f32x4;
typedef __attribute__((ext_vector_type(4))) unsigned short u16x4;
typedef __attribute__((ext_vector_type(4))) unsigned int u32x4;

__device__ __forceinline__ unsigned short f2bf(float f) {
  unsigned int u = __float_as_uint(f);
  return (unsigned short)((u + 0x7fffu + ((u >> 16) & 1u)) >> 16);  // RNE
}
__device__ __forceinline__ bf16x8 ldb8(const unsigned short* p) {
  return *reinterpret_cast<const bf16x8*>(p);
}

// ---- pack weights to bf16 [M][K] ----
__global__ void pack_weights(const float* __restrict__ wc, const float* __restrict__ wcd,
                             const float* __restrict__ wo, const float* __restrict__ wsk,
                             unsigned short* __restrict__ wpc,   // [256][384] k=tap*128+c
                             unsigned short* __restrict__ wpcd,  // [256][96]  zero-pad k>=80
                             unsigned short* __restrict__ wp2)   // [384][128] rows 0-127 Wout, 128-383 Wskip
{
  int idx = blockIdx.x * 256 + threadIdx.x;
  if (idx < 98304) {
    int o = idx / 384, k = idx - o * 384;
    int tap = k >> 7, c = k & 127;
    wpc[idx] = f2bf(wc[(o * 128 + c) * 3 + tap]);
  } else if (idx < 122880) {
    int i = idx - 98304;
    int o = i / 96, k = i - o * 96;
    wpcd[i] = f2bf(k < CCOND ? wcd[o * CCOND + k] : 0.f);
  } else if (idx < 172032) {
    int i = idx - 122880;
    int m = i >> 7, k = i & 127;
    wp2[i] = f2bf(m < 128 ? wo[m * 128 + k] : wsk[(m - 128) * 128 + k]);
  }
}

// ======================= FUSED transpose+k1+k2 (v16) =========================
__global__ __launch_bounds__(512, 4) void k12_fused(
    const unsigned short* __restrict__ wpc, const unsigned short* __restrict__ wpcd,
    const unsigned short* __restrict__ wp2,
    const float* __restrict__ in, const float* __restrict__ cond,
    const float* __restrict__ bconv, const float* __restrict__ bout,
    const float* __restrict__ bskip, float* __restrict__ out)
{
  __shared__ u32x4 ldsX_[XR * 16];        // X [16 gran][120 rows][16B]; z reuses
  __shared__ u32x4 ldsC_[112 * 10];       // cond [10 gran][112 rows][16B]
  char* ldsX = (char*)ldsX_;
  char* ldsC = (char*)ldsC_;

  int b = blockIdx.y;
  int t0 = blockIdx.x * TT;
  int tid = threadIdx.x;
  int lane = tid & 63, w = tid >> 6;            // w 0..7
  int l15 = lane & 15, g = lane >> 4;

  // ---- stage X from raw f32 (lanes = consecutive t: coalesced 256B) ----
  #pragma unroll
  for (int rep = 0; rep < 4; ++rep) {
    int gi = rep * 512 + tid;
    if (gi < 16 * XR) {
      int gch = gi / XR;
      int row = gi - gch * XR;
      int t = t0 - 8 + row;
      u32x4 pk = {};
      if (t >= 0 && t < NT) {
        const float* src = &in[((size_t)b * CIN + gch * 8) * NT + t];
        #pragma unroll
        for (int p = 0; p < 4; ++p) {
          float v0 = src[(size_t)(2 * p) * NT];
          float v1 = src[(size_t)(2 * p + 1) * NT];
          pk[p] = (unsigned)f2bf(v0) | ((unsigned)f2bf(v1) << 16);
        }
      }
      *reinterpret_cast<u32x4*>(&ldsX[gch * XSTRIDE + row * 16]) = pk;
    }
  }
  // ---- stage cond: 10 real granules ----
  #pragma unroll
  for (int rep = 0; rep < 3; ++rep) {
    int gi = rep * 512 + tid;
    if (gi < 10 * TT) {
      int gch = gi / TT;
      int row = gi - gch * TT;
      int t = t0 + row;
      u32x4 pk = {};
      if (t < NT) {
        const float* src = &cond[((size_t)b * CCOND + gch * 8) * NT + t];
        #pragma unroll
        for (int p = 0; p < 4; ++p) {
          float v0 = src[(size_t)(2 * p) * NT];
          float v1 = src[(size_t)(2 * p + 1) * NT];
          pk[p] = (unsigned)f2bf(v0) | ((unsigned)f2bf(v1) << 16);
        }
      }
      *reinterpret_cast<u32x4*>(&ldsC[gch * CSTRIDE + row * 16]) = pk;
    }
  }
  __syncthreads();   // (A) tiles staged

  // ---- k1 (16x16x32): wave w owns rows 16w..+15 (tanh), 128+16w.. (sigmoid) ----
  int rt = 16 * w + l15, rs = 128 + 16 * w + l15;
  f32x4 at[7] = {}, as_[7] = {};

  #pragma unroll
  for (int gg = 0; gg < 5; ++gg) {
    bf16x8 wt[3], wss[3];
    #pragma unroll
    for (int q = 0; q < 3; ++q) {
      int s = gg * 3 + q;
      if (s < 12) {
        int tap = s >> 2, kc = s & 3;
        wt[q]  = ldb8(&wpc[(size_t)rt * 384 + tap * 128 + kc * 32 + g * 8]);
        wss[q] = ldb8(&wpc[(size_t)rs * 384 + tap * 128 + kc * 32 + g * 8]);
      } else {
        int kc = s - 12;
        wt[q]  = ldb8(&wpcd[(size_t)rt * 96 + kc * 32 + g * 8]);
        wss[q] = ldb8(&wpcd[(size_t)rs * 96 + kc * 32 + g * 8]);
      }
    }
    __builtin_amdgcn_sched_barrier(0);   // batch the loads; do not sink/hoist
    #pragma unroll
    for (int q = 0; q < 3; ++q) {
      int s = gg * 3 + q;
      if (s < 12) {
        int tap = s >> 2, kc = s & 3;
        int ck = kc * 4 + g;
        #pragma unroll
        for (int nf = 0; nf < 7; ++nf) {
          int row = nf * 16 + l15 + tap * 4;     // X row (t0-8 origin)
          bf16x8 bfr = *reinterpret_cast<const bf16x8*>(&ldsX[ck * XSTRIDE + row * 16]);
          at[nf]  = __builtin_amdgcn_mfma_f32_16x16x32_bf16(wt[q],  bfr, at[nf],  0, 0, 0);
          as_[nf] = __builtin_amdgcn_mfma_f32_16x16x32_bf16(wss[q], bfr, as_[nf], 0, 0, 0);
        }
      } else {
        int kc = s - 12;
        int ck = kc * 4 + g;                     // 0..11; 10,11 = pad (zero)
        #pragma unroll
        for (int nf = 0; nf < 7; ++nf) {
          int r = nf * 16 + l15;
          bf16x8 bfr = {};
          if (ck < 10) bfr = *reinterpret_cast<const bf16x8*>(&ldsC[ck * CSTRIDE + r * 16]);
          at[nf]  = __builtin_amdgcn_mfma_f32_16x16x32_bf16(wt[q],  bfr, at[nf],  0, 0, 0);
          as_[nf] = __builtin_amdgcn_mfma_f32_16x16x32_bf16(wss[q], bfr, as_[nf], 0, 0, 0);
        }
      }
    }
  }

  float btv[4], bsv[4];
  #pragma unroll
  for (int j = 0; j < 4; ++j) {
    btv[j] = bconv[16 * w + g * 4 + j];
    bsv[j] = bconv[128 + 16 * w + g * 4 + j];
  }

  // preload k2 weights mf=0 (latency hides under barrier+gate)
  bf16x8 wk2buf[2][4];
  #pragma unroll
  for (int kc = 0; kc < 4; ++kc)
    wk2buf[0][kc] = ldb8(&wp2[(size_t)(48 * w + l15) * 128 + kc * 32 + g * 8]);

  __syncthreads();   // (C) X fully consumed; X region becomes z

  // ---- gate in-register -> z into ldsX region [16 gran][rows 0..111] ----
  {
    int cg = 2 * w + (g >> 1);
    int off = (g & 1) * 8;
    #pragma unroll
    for (int nf = 0; nf < 7; ++nf) {
      int tl = nf * 16 + l15;
      u16x4 pk;
      #pragma unroll
      for (int j = 0; j < 4; ++j) {
        float a = at[nf][j] + btv[j];
        float s = as_[nf][j] + bsv[j];
        float z = (1.f - 2.f / (1.f + __expf(2.f * a))) * (1.f / (1.f + __expf(-s)));
        pk[j] = f2bf(z);
      }
      *reinterpret_cast<u16x4*>(&ldsX[cg * XSTRIDE + tl * 16 + off]) = pk;
    }
  }
  __syncthreads();   // (D) z visible

  // ---- k2 (v11 structure): per-mf, weights rotated; granule-major z reads ----
  float* skipp = out + (size_t)NB * 128 * NT;
  #pragma unroll
  for (int mf = 0; mf < 3; ++mf) {
    bf16x8* wcur = wk2buf[mf & 1];
    bf16x8* wnx  = wk2buf[(mf + 1) & 1];
    if (mf < 2) {
      #pragma unroll
      for (int kc = 0; kc < 4; ++kc)
        wnx[kc] = ldb8(&wp2[(size_t)(48 * w + 16 * (mf + 1) + l15) * 128 + kc * 32 + g * 8]);
    }
    __builtin_amdgcn_sched_barrier(0);
    f32x4 am[7] = {};
    #pragma unroll
    for (int kc = 0; kc < 4; ++kc) {
      int gk = kc * 4 + g;
      #pragma unroll
      for (int nf = 0; nf < 7; ++nf) {
        int r = nf * 16 + l15;
        bf16x8 bfr = *reinterpret_cast<const bf16x8*>(&ldsX[gk * XSTRIDE + r * 16]);
        am[nf] = __builtin_amdgcn_mfma_f32_16x16x32_bf16(wcur[kc], bfr, am[nf], 0, 0, 0);
      }
    }
    int mrow = 48 * w + 16 * mf + g * 4;
    #pragma unroll
    for (int j = 0; j < 4; ++j) {
      int m = mrow + j;
      float bv;
      float* basep;
      if (m < 128) { bv = bout[m];        basep = out   + ((size_t)b * 128 + m) * NT; }
      else         { bv = bskip[m - 128]; basep = skipp + ((size_t)b * 256 + (m - 128)) * NT; }
      #pragma unroll
      for (int nf = 0; nf < 7; ++nf) {
        int t = t0 + nf * 16 + l15;
        if (t < NT) basep[t] = am[nf][j] + bv;
      }
    }
  }
}

extern "C" void kernel_launch(void* const* d_in, const int* in_sizes, int n_in,
                              void* d_out, int out_size, void* d_ws, size_t ws_size,
                              hipStream_t stream)
{
  const float* input = (const float*)d_in[0];
  const float* cond  = (const float*)d_in[1];
  const float* wconv = (const float*)d_in[2];
  const float* bconv = (const float*)d_in[3];
  const float* wcond = (const float*)d_in[4];
  const float* wout  = (const float*)d_in[5];
  const float* boutp = (const float*)d_in[6];
  const float* wskip = (const float*)d_in[7];
  const float* bskip = (const float*)d_in[8];
  float* out = (float*)d_out;

  unsigned short* wpc  = (unsigned short*)d_ws;     //  98304 elems
  unsigned short* wpcd = wpc + 98304;               //  24576 elems
  unsigned short* wp2  = wpcd + 24576;              //  49152 elems

  pack_weights<<<672, 256, 0, stream>>>(wconv, wcond, wout, wskip, wpc, wpcd, wp2);
  k12_fused<<<dim3(NBLK, NB), 512, 0, stream>>>(wpc, wpcd, wp2, input, cond,
                                                bconv, boutp, bskip, out);
}

// Round 17
// 99.622 us; speedup vs baseline: 1.2938x; 1.2938x over previous
//
#include <hip/hip_runtime.h>

// WaveNet gated residual block, MI355X bf16-MFMA implementation (v17).
// v17 = v11 VERBATIM (verified best: k12 117us, total 106.4us) with exactly
// ONE change: the k2 epilogue stores go through a per-wave LDS transpose in
// the dead ldsX region (X is dead after k1; barrier D already orders it).
//  - old: 96 scalar global_store_dword per thread, 4x64B segments each
//  - new: fragment -> wave-private slice [16 rows][68 f32] (2-way-free banks,
//         scalar ds_write), aligned ds_read_b128, 24 global_store_dwordx4
//         per thread, 4x256B full-line segments each. No extra barriers.
// v16 lesson: occupancy is NOT LDS-capped (38% at 34.8-67.6KB LDS); that
// lever is dead. v13/14/15 lesson: don't touch k1/k2 compute scheduling.

#define NB 8
#define NT 16000
#define CIN 128
#define CCOND 80
#define CCP 96
#define TT 128
#define NROW 136   // TT + 8 halo

typedef __attribute__((ext_vector_type(8))) __bf16 bf16x8;
typedef __attribute__((ext_vector_type(4))) float f32x4;
typedef __attribute__((ext_vector_type(4))) unsigned short u16x4;
typedef __attribute__((ext_vector_type(4))) unsigned int u32x4;

__device__ __forceinline__ unsigned short f2bf(float f) {
  unsigned int u = __float_as_uint(f);
  return (unsigned short)((u + 0x7fffu + ((u >> 16) & 1u)) >> 16);  // RNE
}
__device__ __forceinline__ bf16x8 ldb8(const unsigned short* p) {
  return *reinterpret_cast<const bf16x8*>(p);
}

// ---- pack weights to bf16 [M][K] ----
__global__ void pack_weights(const float* __restrict__ wc, const float* __restrict__ wcd,
                             const float* __restrict__ wo, const float* __restrict__ wsk,
                             unsigned short* __restrict__ wpc,   // [256][384] k=tap*128+c
                             unsigned short* __restrict__ wpcd,  // [256][96]  zero-pad k>=80
                             unsigned short* __restrict__ wp2)   // [384][128] rows 0-127 Wout, 128-383 Wskip
{
  int idx = blockIdx.x * 256 + threadIdx.x;
  if (idx < 98304) {
    int o = idx / 384, k = idx - o * 384;
    int tap = k >> 7, c = k & 127;
    wpc[idx] = f2bf(wc[(o * 128 + c) * 3 + tap]);
  } else if (idx < 122880) {
    int i = idx - 98304;
    int o = i / 96, k = i - o * 96;
    wpcd[i] = f2bf(k < CCOND ? wcd[o * CCOND + k] : 0.f);
  } else if (idx < 172032) {
    int i = idx - 122880;
    int m = i >> 7, k = i & 127;
    wp2[i] = f2bf(m < 128 ? wo[m * 128 + k] : wsk[(m - 128) * 128 + k]);
  }
}

// ======================= FUSED transpose+k1+k2 (v17) =========================
__global__ __launch_bounds__(512, 4) void k12_fused(
    const unsigned short* __restrict__ wpc, const unsigned short* __restrict__ wpcd,
    const unsigned short* __restrict__ wp2,
    const float* __restrict__ in, const float* __restrict__ cond,
    const float* __restrict__ bconv, const float* __restrict__ bout,
    const float* __restrict__ bskip, float* __restrict__ out)
{
  __shared__ u32x4 ldsX_[2176];  // X tile [136 t-rows][16 granules x 16B], swizzled
  __shared__ u32x4 ldsU_[2048];  // UNION: cond [128][12x16B] / z [128][16x16B]
  char* ldsX = (char*)ldsX_;
  char* ldsU = (char*)ldsU_;

  int b = blockIdx.y;
  int t0 = blockIdx.x * TT;
  int tid = threadIdx.x;
  int lane = tid & 63, w = tid >> 6;            // w 0..7
  int l15 = lane & 15, g = lane >> 4;

  // ---- stage X from raw f32 (lanes = consecutive t: coalesced 256B) ----
  #pragma unroll
  for (int rep = 0; rep < 5; ++rep) {
    int gi = rep * 512 + tid;
    if (gi < 16 * NROW) {
      int gch = gi / NROW;
      int row = gi - gch * NROW;
      int t = t0 - 8 + row;
      u32x4 pk = {};
      if (t >= 0) {
        const float* src = &in[((size_t)b * CIN + gch * 8) * NT + t];
        #pragma unroll
        for (int p = 0; p < 4; ++p) {
          float v0 = src[(size_t)(2 * p) * NT];
          float v1 = src[(size_t)(2 * p + 1) * NT];
          pk[p] = (unsigned)f2bf(v0) | ((unsigned)f2bf(v1) << 16);
        }
      }
      *reinterpret_cast<u32x4*>(&ldsX[row * 256 + ((gch ^ (row & 7)) << 4)]) = pk;
    }
  }
  // ---- stage cond (granules 10,11 zero pad) ----
  #pragma unroll
  for (int rep = 0; rep < 3; ++rep) {
    int gi = rep * 512 + tid;
    int gch = gi >> 7;
    int row = gi & 127;
    u32x4 pk = {};
    if (gch < 10) {
      const float* src = &cond[((size_t)b * CCOND + gch * 8) * NT + t0 + row];
      #pragma unroll
      for (int p = 0; p < 4; ++p) {
        float v0 = src[(size_t)(2 * p) * NT];
        float v1 = src[(size_t)(2 * p + 1) * NT];
        pk[p] = (unsigned)f2bf(v0) | ((unsigned)f2bf(v1) << 16);
      }
    }
    *reinterpret_cast<u32x4*>(&ldsU[row * 192 + ((gch ^ (row & 3)) << 4)]) = pk;
  }
  __syncthreads();

  // ---- k1 (16x16x32): wave w owns rows 16w..+15 (tanh), 128+16w.. (sigmoid) ----
  int rt = 16 * w + l15, rs = 128 + 16 * w + l15;
  f32x4 at[8] = {}, as_[8] = {};

  #pragma unroll
  for (int gg = 0; gg < 5; ++gg) {
    bf16x8 wt[3], wss[3];
    #pragma unroll
    for (int q = 0; q < 3; ++q) {
      int s = gg * 3 + q;
      if (s < 12) {
        int tap = s >> 2, kc = s & 3;
        wt[q]  = ldb8(&wpc[(size_t)rt * 384 + tap * 128 + kc * 32 + g * 8]);
        wss[q] = ldb8(&wpc[(size_t)rs * 384 + tap * 128 + kc * 32 + g * 8]);
      } else {
        int kc = s - 12;
        wt[q]  = ldb8(&wpcd[(size_t)rt * CCP + kc * 32 + g * 8]);
        wss[q] = ldb8(&wpcd[(size_t)rs * CCP + kc * 32 + g * 8]);
      }
    }
    __builtin_amdgcn_sched_barrier(0);   // batch the loads; do not sink/hoist
    #pragma unroll
    for (int q = 0; q < 3; ++q) {
      int s = gg * 3 + q;
      if (s < 12) {
        int tap = s >> 2, kc = s & 3;
        int ck = kc * 4 + g;
        #pragma unroll
        for (int nf = 0; nf < 8; ++nf) {
          int tl = nf * 16 + l15 + tap * 4;
          bf16x8 bfr = *reinterpret_cast<const bf16x8*>(&ldsX[tl * 256 + ((ck ^ (tl & 7)) << 4)]);
          at[nf]  = __builtin_amdgcn_mfma_f32_16x16x32_bf16(wt[q],  bfr, at[nf],  0, 0, 0);
          as_[nf] = __builtin_amdgcn_mfma_f32_16x16x32_bf16(wss[q], bfr, as_[nf], 0, 0, 0);
        }
      } else {
        int kc = s - 12;
        int ck = kc * 4 + g;
        #pragma unroll
        for (int nf = 0; nf < 8; ++nf) {
          int r = nf * 16 + l15;
          bf16x8 bfr = *reinterpret_cast<const bf16x8*>(&ldsU[r * 192 + ((ck ^ (r & 3)) << 4)]);
          at[nf]  = __builtin_amdgcn_mfma_f32_16x16x32_bf16(wt[q],  bfr, at[nf],  0, 0, 0);
          as_[nf] = __builtin_amdgcn_mfma_f32_16x16x32_bf16(wss[q], bfr, as_[nf], 0, 0, 0);
        }
      }
    }
  }

  float btv[4], bsv[4];
  #pragma unroll
  for (int j = 0; j < 4; ++j) {
    btv[j] = bconv[16 * w + g * 4 + j];
    bsv[j] = bconv[128 + 16 * w + g * 4 + j];
  }

  // preload k2 weights mf=0 (latency hides under barrier+gate)
  bf16x8 wk2buf[2][4];
  #pragma unroll
  for (int kc = 0; kc < 4; ++kc)
    wk2buf[0][kc] = ldb8(&wp2[(size_t)(48 * w + l15) * 128 + kc * 32 + g * 8]);

  __syncthreads();   // cond region consumed; ldsU becomes z

  // ---- gate in-register -> z into swizzled ldsU [128 rows][256B] ----
  {
    int cg = 2 * w + (g >> 1);
    int off = (g & 1) * 8;
    #pragma unroll
    for (int nf = 0; nf < 8; ++nf) {
      int tl = nf * 16 + l15;
      u16x4 pk;
      #pragma unroll
      for (int j = 0; j < 4; ++j) {
        float a = at[nf][j] + btv[j];
        float s = as_[nf][j] + bsv[j];
        float z = (1.f - 2.f / (1.f + __expf(2.f * a))) * (1.f / (1.f + __expf(-s)));
        pk[j] = f2bf(z);
      }
      *reinterpret_cast<u16x4*>(&ldsU[tl * 256 + ((cg ^ (tl & 7)) << 4) + off]) = pk;
    }
  }
  __syncthreads();   // (D) z visible; ldsX now dead -> reused as store slices

  // ---- k2 (v11 structure): per-mf, rotated weights; NEW vectorized epilogue ----
  float* skipp = out + (size_t)NB * 128 * NT;
  float* slice = (float*)(ldsX + w * 4352);     // wave-private [16 rows][68 f32]
  #pragma unroll
  for (int mf = 0; mf < 3; ++mf) {
    bf16x8* wcur = wk2buf[mf & 1];
    bf16x8* wnx  = wk2buf[(mf + 1) & 1];
    if (mf < 2) {
      #pragma unroll
      for (int kc = 0; kc < 4; ++kc)
        wnx[kc] = ldb8(&wp2[(size_t)(48 * w + 16 * (mf + 1) + l15) * 128 + kc * 32 + g * 8]);
    }
    __builtin_amdgcn_sched_barrier(0);
    f32x4 am[8] = {};
    #pragma unroll
    for (int kc = 0; kc < 4; ++kc) {
      #pragma unroll
      for (int nf = 0; nf < 8; ++nf) {
        int r = nf * 16 + l15;
        bf16x8 bfr = *reinterpret_cast<const bf16x8*>(&ldsU[r * 256 + (((kc * 4 + g) ^ (r & 7)) << 4)]);
        am[nf] = __builtin_amdgcn_mfma_f32_16x16x32_bf16(wcur[kc], bfr, am[nf], 0, 0, 0);
      }
    }
    // epilogue: fragment -> wave-private slice -> float4 global stores
    int mb = 48 * w + 16 * mf;
    float bvv[4];
    const float* bp;
    float* gbase;
    if (mb < 128) { bp = bout + mb;          gbase = out   + ((size_t)b * 128 + mb) * NT; }
    else          { bp = bskip + (mb - 128); gbase = skipp + ((size_t)b * 256 + (mb - 128)) * NT; }
    #pragma unroll
    for (int j = 0; j < 4; ++j) bvv[j] = bp[g * 4 + j];

    #pragma unroll
    for (int half = 0; half < 2; ++half) {
      // write 16 rows x 64 t fragment into slice [16][68] (2-way banks, free)
      #pragma unroll
      for (int nf2 = 0; nf2 < 4; ++nf2) {
        int nf = half * 4 + nf2;
        #pragma unroll
        for (int j = 0; j < 4; ++j)
          slice[(g * 4 + j) * 68 + nf2 * 16 + l15] = am[nf][j] + bvv[j];
      }
      // read back as float4 along t (aligned b128), store 4x256B segments/instr
      #pragma unroll
      for (int p = 0; p < 4; ++p) {
        int row = p * 4 + (lane >> 4);            // 0..15
        f32x4 v = *reinterpret_cast<const f32x4*>(&slice[row * 68 + (lane & 15) * 4]);
        *reinterpret_cast<f32x4*>(&gbase[(size_t)row * NT + t0 + half * 64 + (lane & 15) * 4]) = v;
      }
    }
  }
}

extern "C" void kernel_launch(void* const* d_in, const int* in_sizes, int n_in,
                              void* d_out, int out_size, void* d_ws, size_t ws_size,
                              hipStream_t stream)
{
  const float* input = (const float*)d_in[0];
  const float* cond  = (const float*)d_in[1];
  const float* wconv = (const float*)d_in[2];
  const float* bconv = (const float*)d_in[3];
  const float* wcond = (const float*)d_in[4];
  const float* wout  = (const float*)d_in[5];
  const float* boutp = (const float*)d_in[6];
  const float* wskip = (const float*)d_in[7];
  const float* bskip = (const float*)d_in[8];
  float* out = (float*)d_out;

  unsigned short* wpc  = (unsigned short*)d_ws;     //  98304 elems
  unsigned short* wpcd = wpc + 98304;               //  24576 elems
  unsigned short* wp2  = wpcd + 24576;              //  49152 elems

  pack_weights<<<672, 256, 0, stream>>>(wconv, wcond, wout, wskip, wpc, wpcd, wp2);
  k12_fused<<<dim3(NT / TT, NB), 512, 0, stream>>>(wpc, wpcd, wp2, input, cond,
                                                   bconv, boutp, bskip, out);
}

// Round 18
// 93.245 us; speedup vs baseline: 1.3823x; 1.0684x over previous
//
#include <hip/hip_runtime.h>

// WaveNet gated residual block, MI355X bf16-MFMA implementation (v18).
// v18 = v17 VERBATIM (verified best: total 99.6us) + VALU diet ONLY:
//  - v_cvt_pk_bf16_f32 (1 instr, RNE) replaces the 4-op f2bf bit-twiddle in
//    X/cond staging and the gate (~460 VALU ops/thread saved).
//  - raw v_rcp_f32 replaces compiler rcp+Newton in the two gate divisions
//    (rel err ~1e-5 << bf16 quantization; exp->inf->rcp->0 saturates right).
// No schedule, liveness, LDS, or store-path changes (v13-v16 lessons).
// VALUBusy 26% ~= 30us on the serialized critical path; predict -4..-7us.

#define NB 8
#define NT 16000
#define CIN 128
#define CCOND 80
#define CCP 96
#define TT 128
#define NROW 136   // TT + 8 halo

typedef __attribute__((ext_vector_type(8))) __bf16 bf16x8;
typedef __attribute__((ext_vector_type(4))) float f32x4;
typedef __attribute__((ext_vector_type(2))) unsigned int u32x2;
typedef __attribute__((ext_vector_type(4))) unsigned int u32x4;

__device__ __forceinline__ unsigned short f2bf(float f) {
  unsigned int u = __float_as_uint(f);
  return (unsigned short)((u + 0x7fffu + ((u >> 16) & 1u)) >> 16);  // RNE
}
__device__ __forceinline__ unsigned cvtpk(float lo, float hi) {
  unsigned r;
  asm("v_cvt_pk_bf16_f32 %0, %1, %2" : "=v"(r) : "v"(lo), "v"(hi));
  return r;
}
__device__ __forceinline__ float rcpf(float x) {
  float r;
  asm("v_rcp_f32 %0, %1" : "=v"(r) : "v"(x));
  return r;
}
__device__ __forceinline__ bf16x8 ldb8(const unsigned short* p) {
  return *reinterpret_cast<const bf16x8*>(p);
}

// ---- pack weights to bf16 [M][K] ----
__global__ void pack_weights(const float* __restrict__ wc, const float* __restrict__ wcd,
                             const float* __restrict__ wo, const float* __restrict__ wsk,
                             unsigned short* __restrict__ wpc,   // [256][384] k=tap*128+c
                             unsigned short* __restrict__ wpcd,  // [256][96]  zero-pad k>=80
                             unsigned short* __restrict__ wp2)   // [384][128] rows 0-127 Wout, 128-383 Wskip
{
  int idx = blockIdx.x * 256 + threadIdx.x;
  if (idx < 98304) {
    int o = idx / 384, k = idx - o * 384;
    int tap = k >> 7, c = k & 127;
    wpc[idx] = f2bf(wc[(o * 128 + c) * 3 + tap]);
  } else if (idx < 122880) {
    int i = idx - 98304;
    int o = i / 96, k = i - o * 96;
    wpcd[i] = f2bf(k < CCOND ? wcd[o * CCOND + k] : 0.f);
  } else if (idx < 172032) {
    int i = idx - 122880;
    int m = i >> 7, k = i & 127;
    wp2[i] = f2bf(m < 128 ? wo[m * 128 + k] : wsk[(m - 128) * 128 + k]);
  }
}

// ======================= FUSED transpose+k1+k2 (v18) =========================
__global__ __launch_bounds__(512, 4) void k12_fused(
    const unsigned short* __restrict__ wpc, const unsigned short* __restrict__ wpcd,
    const unsigned short* __restrict__ wp2,
    const float* __restrict__ in, const float* __restrict__ cond,
    const float* __restrict__ bconv, const float* __restrict__ bout,
    const float* __restrict__ bskip, float* __restrict__ out)
{
  __shared__ u32x4 ldsX_[2176];  // X tile [136 t-rows][16 granules x 16B], swizzled
  __shared__ u32x4 ldsU_[2048];  // UNION: cond [128][12x16B] / z [128][16x16B]
  char* ldsX = (char*)ldsX_;
  char* ldsU = (char*)ldsU_;

  int b = blockIdx.y;
  int t0 = blockIdx.x * TT;
  int tid = threadIdx.x;
  int lane = tid & 63, w = tid >> 6;            // w 0..7
  int l15 = lane & 15, g = lane >> 4;

  // ---- stage X from raw f32 (lanes = consecutive t: coalesced 256B) ----
  #pragma unroll
  for (int rep = 0; rep < 5; ++rep) {
    int gi = rep * 512 + tid;
    if (gi < 16 * NROW) {
      int gch = gi / NROW;
      int row = gi - gch * NROW;
      int t = t0 - 8 + row;
      u32x4 pk = {};
      if (t >= 0) {
        const float* src = &in[((size_t)b * CIN + gch * 8) * NT + t];
        #pragma unroll
        for (int p = 0; p < 4; ++p)
          pk[p] = cvtpk(src[(size_t)(2 * p) * NT], src[(size_t)(2 * p + 1) * NT]);
      }
      *reinterpret_cast<u32x4*>(&ldsX[row * 256 + ((gch ^ (row & 7)) << 4)]) = pk;
    }
  }
  // ---- stage cond (granules 10,11 zero pad) ----
  #pragma unroll
  for (int rep = 0; rep < 3; ++rep) {
    int gi = rep * 512 + tid;
    int gch = gi >> 7;
    int row = gi & 127;
    u32x4 pk = {};
    if (gch < 10) {
      const float* src = &cond[((size_t)b * CCOND + gch * 8) * NT + t0 + row];
      #pragma unroll
      for (int p = 0; p < 4; ++p)
        pk[p] = cvtpk(src[(size_t)(2 * p) * NT], src[(size_t)(2 * p + 1) * NT]);
    }
    *reinterpret_cast<u32x4*>(&ldsU[row * 192 + ((gch ^ (row & 3)) << 4)]) = pk;
  }
  __syncthreads();

  // ---- k1 (16x16x32): wave w owns rows 16w..+15 (tanh), 128+16w.. (sigmoid) ----
  int rt = 16 * w + l15, rs = 128 + 16 * w + l15;
  f32x4 at[8] = {}, as_[8] = {};

  #pragma unroll
  for (int gg = 0; gg < 5; ++gg) {
    bf16x8 wt[3], wss[3];
    #pragma unroll
    for (int q = 0; q < 3; ++q) {
      int s = gg * 3 + q;
      if (s < 12) {
        int tap = s >> 2, kc = s & 3;
        wt[q]  = ldb8(&wpc[(size_t)rt * 384 + tap * 128 + kc * 32 + g * 8]);
        wss[q] = ldb8(&wpc[(size_t)rs * 384 + tap * 128 + kc * 32 + g * 8]);
      } else {
        int kc = s - 12;
        wt[q]  = ldb8(&wpcd[(size_t)rt * CCP + kc * 32 + g * 8]);
        wss[q] = ldb8(&wpcd[(size_t)rs * CCP + kc * 32 + g * 8]);
      }
    }
    __builtin_amdgcn_sched_barrier(0);   // batch the loads; do not sink/hoist
    #pragma unroll
    for (int q = 0; q < 3; ++q) {
      int s = gg * 3 + q;
      if (s < 12) {
        int tap = s >> 2, kc = s & 3;
        int ck = kc * 4 + g;
        #pragma unroll
        for (int nf = 0; nf < 8; ++nf) {
          int tl = nf * 16 + l15 + tap * 4;
          bf16x8 bfr = *reinterpret_cast<const bf16x8*>(&ldsX[tl * 256 + ((ck ^ (tl & 7)) << 4)]);
          at[nf]  = __builtin_amdgcn_mfma_f32_16x16x32_bf16(wt[q],  bfr, at[nf],  0, 0, 0);
          as_[nf] = __builtin_amdgcn_mfma_f32_16x16x32_bf16(wss[q], bfr, as_[nf], 0, 0, 0);
        }
      } else {
        int kc = s - 12;
        int ck = kc * 4 + g;
        #pragma unroll
        for (int nf = 0; nf < 8; ++nf) {
          int r = nf * 16 + l15;
          bf16x8 bfr = *reinterpret_cast<const bf16x8*>(&ldsU[r * 192 + ((ck ^ (r & 3)) << 4)]);
          at[nf]  = __builtin_amdgcn_mfma_f32_16x16x32_bf16(wt[q],  bfr, at[nf],  0, 0, 0);
          as_[nf] = __builtin_amdgcn_mfma_f32_16x16x32_bf16(wss[q], bfr, as_[nf], 0, 0, 0);
        }
      }
    }
  }

  float btv[4], bsv[4];
  #pragma unroll
  for (int j = 0; j < 4; ++j) {
    btv[j] = bconv[16 * w + g * 4 + j];
    bsv[j] = bconv[128 + 16 * w + g * 4 + j];
  }

  // preload k2 weights mf=0 (latency hides under barrier+gate)
  bf16x8 wk2buf[2][4];
  #pragma unroll
  for (int kc = 0; kc < 4; ++kc)
    wk2buf[0][kc] = ldb8(&wp2[(size_t)(48 * w + l15) * 128 + kc * 32 + g * 8]);

  __syncthreads();   // cond region consumed; ldsU becomes z

  // ---- gate in-register -> z into swizzled ldsU [128 rows][256B] ----
  {
    int cg = 2 * w + (g >> 1);
    int off = (g & 1) * 8;
    #pragma unroll
    for (int nf = 0; nf < 8; ++nf) {
      int tl = nf * 16 + l15;
      float zv[4];
      #pragma unroll
      for (int j = 0; j < 4; ++j) {
        float a = at[nf][j] + btv[j];
        float s = as_[nf][j] + bsv[j];
        float th = 1.f - 2.f * rcpf(1.f + __expf(2.f * a));   // tanh(a)
        float sg = rcpf(1.f + __expf(-s));                    // sigmoid(s)
        zv[j] = th * sg;
      }
      u32x2 pk;
      pk[0] = cvtpk(zv[0], zv[1]);
      pk[1] = cvtpk(zv[2], zv[3]);
      *reinterpret_cast<u32x2*>(&ldsU[tl * 256 + ((cg ^ (tl & 7)) << 4) + off]) = pk;
    }
  }
  __syncthreads();   // (D) z visible; ldsX now dead -> reused as store slices

  // ---- k2 (v11 structure): per-mf, rotated weights; vectorized epilogue ----
  float* skipp = out + (size_t)NB * 128 * NT;
  float* slice = (float*)(ldsX + w * 4352);     // wave-private [16 rows][68 f32]
  #pragma unroll
  for (int mf = 0; mf < 3; ++mf) {
    bf16x8* wcur = wk2buf[mf & 1];
    bf16x8* wnx  = wk2buf[(mf + 1) & 1];
    if (mf < 2) {
      #pragma unroll
      for (int kc = 0; kc < 4; ++kc)
        wnx[kc] = ldb8(&wp2[(size_t)(48 * w + 16 * (mf + 1) + l15) * 128 + kc * 32 + g * 8]);
    }
    __builtin_amdgcn_sched_barrier(0);
    f32x4 am[8] = {};
    #pragma unroll
    for (int kc = 0; kc < 4; ++kc) {
      #pragma unroll
      for (int nf = 0; nf < 8; ++nf) {
        int r = nf * 16 + l15;
        bf16x8 bfr = *reinterpret_cast<const bf16x8*>(&ldsU[r * 256 + (((kc * 4 + g) ^ (r & 7)) << 4)]);
        am[nf] = __builtin_amdgcn_mfma_f32_16x16x32_bf16(wcur[kc], bfr, am[nf], 0, 0, 0);
      }
    }
    // epilogue: fragment -> wave-private slice -> float4 global stores
    int mb = 48 * w + 16 * mf;
    float bvv[4];
    const float* bp;
    float* gbase;
    if (mb < 128) { bp = bout + mb;          gbase = out   + ((size_t)b * 128 + mb) * NT; }
    else          { bp = bskip + (mb - 128); gbase = skipp + ((size_t)b * 256 + (mb - 128)) * NT; }
    #pragma unroll
    for (int j = 0; j < 4; ++j) bvv[j] = bp[g * 4 + j];

    #pragma unroll
    for (int half = 0; half < 2; ++half) {
      // write 16 rows x 64 t fragment into slice [16][68] (2-way banks, ~free)
      #pragma unroll
      for (int nf2 = 0; nf2 < 4; ++nf2) {
        int nf = half * 4 + nf2;
        #pragma unroll
        for (int j = 0; j < 4; ++j)
          slice[(g * 4 + j) * 68 + nf2 * 16 + l15] = am[nf][j] + bvv[j];
      }
      // read back as float4 along t (aligned b128), store 4x256B segments/instr
      #pragma unroll
      for (int p = 0; p < 4; ++p) {
        int row = p * 4 + (lane >> 4);            // 0..15
        f32x4 v = *reinterpret_cast<const f32x4*>(&slice[row * 68 + (lane & 15) * 4]);
        *reinterpret_cast<f32x4*>(&gbase[(size_t)row * NT + t0 + half * 64 + (lane & 15) * 4]) = v;
      }
    }
  }
}

extern "C" void kernel_launch(void* const* d_in, const int* in_sizes, int n_in,
                              void* d_out, int out_size, void* d_ws, size_t ws_size,
                              hipStream_t stream)
{
  const float* input = (const float*)d_in[0];
  const float* cond  = (const float*)d_in[1];
  const float* wconv = (const float*)d_in[2];
  const float* bconv = (const float*)d_in[3];
  const float* wcond = (const float*)d_in[4];
  const float* wout  = (const float*)d_in[5];
  const float* boutp = (const float*)d_in[6];
  const float* wskip = (const float*)d_in[7];
  const float* bskip = (const float*)d_in[8];
  float* out = (float*)d_out;

  unsigned short* wpc  = (unsigned short*)d_ws;     //  98304 elems
  unsigned short* wpcd = wpc + 98304;               //  24576 elems
  unsigned short* wp2  = wpcd + 24576;              //  49152 elems

  pack_weights<<<672, 256, 0, stream>>>(wconv, wcond, wout, wskip, wpc, wpcd, wp2);
  k12_fused<<<dim3(NT / TT, NB), 512, 0, stream>>>(wpc, wpcd, wp2, input, cond,
                                                   bconv, boutp, bskip, out);
}